// Round 7
// baseline (260.773 us; speedup 1.0000x reference)
//
#include <hip/hip_runtime.h>
#include <cstdint>

#define D_MODEL 1024
#define NHEADS 16
#define DKH 64
#define SEQL 2048
#define NBATCH 2
#define NROWS (NBATCH * SEQL) /* 4096 */

typedef __bf16 bf16;
typedef __bf16 bf16x2 __attribute__((ext_vector_type(2)));
typedef __bf16 bf16x4 __attribute__((ext_vector_type(4)));
typedef __bf16 bf16x8 __attribute__((ext_vector_type(8)));
typedef float f32x4 __attribute__((ext_vector_type(4)));
typedef float f32x16 __attribute__((ext_vector_type(16)));
typedef unsigned u32x4 __attribute__((ext_vector_type(4)));

static __device__ __forceinline__ f32x4 mfma16(bf16x8 a, bf16x8 b, f32x4 c) {
  return __builtin_amdgcn_mfma_f32_16x16x32_bf16(a, b, c, 0, 0, 0);
}

static __device__ __forceinline__ f32x16 mfma32(bf16x8 a, bf16x8 b, f32x16 c) {
  return __builtin_amdgcn_mfma_f32_32x32x16_bf16(a, b, c, 0, 0, 0);
}

static __device__ __forceinline__ void gload_lds16(const bf16* g, bf16* l) {
  __builtin_amdgcn_global_load_lds(
      (const __attribute__((address_space(1))) void*)g,
      (__attribute__((address_space(3))) void*)l, 16, 0, 0);
}

// raw v_exp_f32 (libm exp2f adds ~10 range-check instrs; HW handles our full
// input range incl. -1e30 -> 0)
static __device__ __forceinline__ float fexp2(float x) {
  return __builtin_amdgcn_exp2f(x);
}

// pack two f32 -> one dword of two bf16 (RNE), lo = a, hi = b
static __device__ __forceinline__ unsigned cvt_pk(float a, float b) {
  unsigned r;
  asm("v_cvt_pk_bf16_f32 %0, %1, %2" : "=v"(r) : "v"(a), "v"(b));
  return r;
}

// swap lanes 32-63 of a with lanes 0-31 of b (VALU pipe, not LDS)
static __device__ __forceinline__ void plswap(unsigned& a, unsigned& b) {
  asm("v_permlane32_swap_b32 %0, %1" : "+v"(a), "+v"(b));
}

// ---------------------------------------------------------------------------
// fp32 -> bf16 conversion of x and the 4 weight matrices.
// ---------------------------------------------------------------------------
__global__ __launch_bounds__(256) void convert_kernel(
    const float* __restrict__ x, const float* __restrict__ wq,
    const float* __restrict__ wk, const float* __restrict__ wv,
    const float* __restrict__ wo, bf16* __restrict__ xb,
    bf16* __restrict__ wqb, bf16* __restrict__ wkb, bf16* __restrict__ wvb,
    bf16* __restrict__ wob) {
  int i4 = blockIdx.x * 256 + threadIdx.x;
  const float* src;
  bf16* dst;
  int off;
  if (i4 < (NROWS * D_MODEL / 4)) {
    src = x; dst = xb; off = i4;
  } else {
    int j = i4 - NROWS * D_MODEL / 4;
    int sel = j >> 18;
    off = j & ((1 << 18) - 1);
    src = sel == 0 ? wq : sel == 1 ? wk : sel == 2 ? wv : wo;
    dst = sel == 0 ? wqb : sel == 1 ? wkb : sel == 2 ? wvb : wob;
  }
  float4 v = ((const float4*)src)[off];
  bf16x4 o;
  o[0] = (bf16)v.x; o[1] = (bf16)v.y; o[2] = (bf16)v.z; o[3] = (bf16)v.w;
  ((bf16x4*)dst)[off] = o;
}

// ---------------------------------------------------------------------------
// FUSED QKV GEMM + RoPE. One block: Q,K,V for (128 tokens x 64 e-cols);
// A tile staged once, 3 B tiles together (MFMA:glds = 48:10). RoPE applied
// to the f32 Q/K accumulators in the epilogue: the (even,odd) column pair
// lives in adjacent lanes (l16^1) -> __shfl_xor(v,1); Q pre-scaled by
// 0.125*log2e. V stored transposed (Vt[e][token]) via packed b64 stores.
// LDS: A 16K + 3x8K = 40960 B.
// ---------------------------------------------------------------------------
__global__ __launch_bounds__(256, 3) void qkv_gemm(
    const bf16* __restrict__ A, const bf16* __restrict__ Bq,
    const bf16* __restrict__ Bk, const bf16* __restrict__ Bv,
    const int* __restrict__ tpos, bf16* __restrict__ Qb,
    bf16* __restrict__ Kb, bf16* __restrict__ Vt) {
  __shared__ bf16 As[128 * 64];
  __shared__ bf16 Bs[3][64 * 64];
  const int t = threadIdx.x, wave = t >> 6, lane = t & 63;
  const int quad = lane >> 4, l16 = lane & 15;
  const int bm = blockIdx.x * 128, bn = blockIdx.y * 64;

  f32x4 acc[3][2][4];
  for (int o = 0; o < 3; o++)
    for (int mt = 0; mt < 2; mt++)
      for (int nt = 0; nt < 4; nt++)
        for (int r = 0; r < 4; r++) acc[o][mt][nt][r] = 0.0f;

  for (int k0 = 0; k0 < D_MODEL; k0 += 64) {
    for (int j = 0; j < 4; j++) {
      int s = (wave * 4 + j) * 64 + lane;
      int srow = s >> 3, scol = (s & 7) ^ (srow & 7);
      gload_lds16(&A[(size_t)(bm + srow) * D_MODEL + k0 + scol * 8],
                  &As[(wave * 4 + j) * 512]);
    }
    for (int j = 0; j < 2; j++) {
      int s = (wave * 2 + j) * 64 + lane;
      int srow = s >> 3, scol = (s & 7) ^ (srow & 7);
      size_t goff = (size_t)(bn + srow) * D_MODEL + k0 + scol * 8;
      gload_lds16(&Bq[goff], &Bs[0][(wave * 2 + j) * 512]);
      gload_lds16(&Bk[goff], &Bs[1][(wave * 2 + j) * 512]);
      gload_lds16(&Bv[goff], &Bs[2][(wave * 2 + j) * 512]);
    }
    __syncthreads();
    for (int kh = 0; kh < 2; kh++) {
      const int kc = kh * 4 + quad;
      bf16x8 af[2];
      for (int mt = 0; mt < 2; mt++) {
        int row = wave * 32 + mt * 16 + l16;
        af[mt] = *(bf16x8*)&As[row * 64 + (kc ^ (row & 7)) * 8];
      }
      for (int nt = 0; nt < 4; nt++) {
        int row = nt * 16 + l16;
        int off = row * 64 + (kc ^ (row & 7)) * 8;
        bf16x8 bq = *(bf16x8*)&Bs[0][off];
        bf16x8 bk = *(bf16x8*)&Bs[1][off];
        bf16x8 bv = *(bf16x8*)&Bs[2][off];
        for (int mt = 0; mt < 2; mt++) {
          acc[0][mt][nt] = mfma16(af[mt], bq, acc[0][mt][nt]);
          acc[1][mt][nt] = mfma16(af[mt], bk, acc[1][mt][nt]);
          acc[2][mt][nt] = mfma16(af[mt], bv, acc[2][mt][nt]);
        }
      }
    }
    __syncthreads();
  }

  // ---- epilogue: RoPE on Q,K (f32 regs, pair via shfl), stores ----
  const float qsc = 0.125f * 1.44269504f;
  float freqv[4], sgn[4];
  for (int nt = 0; nt < 4; nt++) {
    int cp = (bn + nt * 16 + l16) & 63;
    freqv[nt] = fexp2((float)(cp >> 1) * -0.41524101f);  // 10000^(-p/32)
    sgn[nt] = (cp & 1) ? 1.0f : -1.0f;
  }
  for (int mt = 0; mt < 2; mt++) {
    int row0 = bm + wave * 32 + mt * 16 + quad * 4;
    for (int r = 0; r < 4; r++) {
      int row = row0 + r;
      float pos = (float)tpos[row & (SEQL - 1)];
      for (int nt = 0; nt < 4; nt++) {
        int col = bn + nt * 16 + l16;
        float sn, cs;
        __sincosf(pos * freqv[nt], &sn, &cs);
        float vq = acc[0][mt][nt][r];
        float vk = acc[1][mt][nt][r];
        float pq = __shfl_xor(vq, 1);
        float pk = __shfl_xor(vk, 1);
        float rq = vq * cs + sgn[nt] * pq * sn;
        float rk = vk * cs + sgn[nt] * pk * sn;
        Qb[(size_t)row * D_MODEL + col] = (bf16)(rq * qsc);
        Kb[(size_t)row * D_MODEL + col] = (bf16)rk;
      }
    }
    for (int nt = 0; nt < 4; nt++) {
      int col = bn + nt * 16 + l16;
      bf16x4 pv;
      for (int r = 0; r < 4; r++) pv[r] = (bf16)acc[2][mt][nt][r];
      *(bf16x4*)&Vt[(size_t)col * NROWS + row0] = pv;  // transposed, packed
    }
  }
}

// ---------------------------------------------------------------------------
// og_norm, R16: o_gemm with normalize FUSED into the A-operand staging.
// Rationale: all 5 kernels are individually <40us but total=182 -> ~60us is
// inter-kernel launch/serialization overhead; kernel-count reduction is the
// lever. Each K-step kt is exactly head h=kt (DKH=64), so inv_l is
// per-(row,kt): A-tile = (sum of O slices) * (1/sum of L slices), computed
// in regs from f32 partials, cvt to bf16, swizzled ds_write. B (wob) stays
// gload_lds. Removes the normalize kernel + the Cc 8.4MB round-trip.
// LDS: As 8K + Bs 16K = 24KB. Single-buffer drain (pipeline variants
// measured ~0 in R3-R6; multi-block occupancy covers stage latency).
// ---------------------------------------------------------------------------
__global__ __launch_bounds__(256, 3) void og_norm(
    const float* __restrict__ O0, const float* __restrict__ O1,
    const float* __restrict__ O2, const float* __restrict__ O3,
    const float* __restrict__ L0, const float* __restrict__ L1,
    const float* __restrict__ L2, const float* __restrict__ L3,
    const bf16* __restrict__ Bm, float* __restrict__ C) {
  constexpr int MT = 2, NT = 4;
  const int bm = blockIdx.x * 64, bn = blockIdx.y * 128;
  __shared__ bf16 As[64 * 64];
  __shared__ bf16 Bs[128 * 64];
  const int t = threadIdx.x;
  const int wave = t >> 6, lane = t & 63;
  const int quad = lane >> 4, l16 = lane & 15;
  const int wm = (wave >> 1) * 32, wn = (wave & 1) * 64;
  const int tr = t >> 4, tc = t & 15;  // A-stage: rows tr+16rr, cols tc*4..+3

  f32x4 acc[MT][NT];
  for (int i = 0; i < MT; i++)
    for (int j = 0; j < NT; j++)
      for (int r = 0; r < 4; r++) acc[i][j][r] = 0.0f;

  for (int kt = 0; kt < 16; kt++) {
    __syncthreads();  // previous compute's As/Bs reads done
    // ---- B stage: gload_lds, 4 per thread ----
#pragma unroll
    for (int j = 0; j < 4; j++) {
      int s = (wave * 4 + j) * 64 + lane;
      int srow = s >> 3, scol = (s & 7) ^ (srow & 7);
      gload_lds16(&Bm[(size_t)(bn + srow) * D_MODEL + kt * 64 + scol * 8],
                  &Bs[(wave * 4 + j) * 512]);
    }
    // ---- A stage: normalize-fused (head h = kt) ----
    const int h = kt;
#pragma unroll
    for (int rr = 0; rr < 4; rr++) {
      int rl = tr + rr * 16;  // 0..63
      int grow = bm + rl;
      int s = grow & (SEQL - 1), b = grow >> 11;
      float l = L0[(size_t)grow * NHEADS + h];
      f32x4 v = *(const f32x4*)&O0[(size_t)grow * D_MODEL + kt * 64 + tc * 4];
      if (s >= 512) {
        size_t r1 = (size_t)b * (SEQL - 512) + (s - 512);
        l += L1[r1 * NHEADS + h];
        f32x4 u = *(const f32x4*)&O1[r1 * D_MODEL + kt * 64 + tc * 4];
        for (int r = 0; r < 4; r++) v[r] += u[r];
      }
      if (s >= 1024) {
        size_t r2 = (size_t)b * (SEQL - 1024) + (s - 1024);
        l += L2[r2 * NHEADS + h];
        f32x4 u = *(const f32x4*)&O2[r2 * D_MODEL + kt * 64 + tc * 4];
        for (int r = 0; r < 4; r++) v[r] += u[r];
      }
      if (s >= 1536) {
        size_t r3 = (size_t)b * (SEQL - 1536) + (s - 1536);
        l += L3[r3 * NHEADS + h];
        f32x4 u = *(const f32x4*)&O3[r3 * D_MODEL + kt * 64 + tc * 4];
        for (int r = 0; r < 4; r++) v[r] += u[r];
      }
      float inv = 1.0f / l;
      bf16x4 o;
      for (int r = 0; r < 4; r++) o[r] = (bf16)(v[r] * inv);
      // swizzled write: chunk c = tc>>1, half = tc&1
      *(bf16x4*)&As[rl * 64 + ((tc >> 1) ^ (rl & 7)) * 8 + (tc & 1) * 4] = o;
    }
    __syncthreads();  // drains vmcnt (gload_lds) + lgkm (ds_write)
    // ---- compute ----
#pragma unroll
    for (int kh = 0; kh < 2; kh++) {
      const int kc = kh * 4 + quad;
      bf16x8 af[MT], bfr[NT];
#pragma unroll
      for (int mt = 0; mt < MT; mt++) {
        int row = wm + mt * 16 + l16;
        af[mt] = *(bf16x8*)&As[row * 64 + (kc ^ (row & 7)) * 8];
      }
#pragma unroll
      for (int nt = 0; nt < NT; nt++) {
        int row = wn + nt * 16 + l16;
        bfr[nt] = *(bf16x8*)&Bs[row * 64 + (kc ^ (row & 7)) * 8];
      }
#pragma unroll
      for (int mt = 0; mt < MT; mt++)
#pragma unroll
        for (int nt = 0; nt < NT; nt++)
          acc[mt][nt] = mfma16(af[mt], bfr[nt], acc[mt][nt]);
    }
  }
  for (int mt = 0; mt < MT; mt++)
    for (int nt = 0; nt < NT; nt++)
      for (int r = 0; r < 4; r++) {
        int row = bm + wm + mt * 16 + quad * 4 + r;
        int col = bn + wn + nt * 16 + l16;
        C[(size_t)row * D_MODEL + col] = acc[mt][nt][r];
      }
}

// ---------------------------------------------------------------------------
// Flash attention, causal, transposed-score, static-scale, no atomics.
// R12/R3 structure (best measured: attn <= 40.8us): 2-phase double-buffered
// staging, 64-key half-tiles, Kh[2]+Vh[2] in 32KB LDS, counted vmcnt(4)
// (never 0 mid-loop), raw s_barrier fenced by sched_barrier(0) + memory
// clobbers. Depth ladder measured R2-R5: depth0=92us, 0.5=43.4, 1=40.8,
// 2=41 -> depth saturates at 1; attn frozen here.
// ---------------------------------------------------------------------------
__global__ __launch_bounds__(256) void attn_kernel(
    const bf16* __restrict__ Q, const bf16* __restrict__ K,
    const bf16* __restrict__ Vt_g, float* __restrict__ O0,
    float* __restrict__ O1, float* __restrict__ O2, float* __restrict__ O3,
    float* __restrict__ L0, float* __restrict__ L1, float* __restrict__ L2,
    float* __restrict__ L3) {
  const int t = threadIdx.x;
  const int wave = t >> 6, lane = t & 63;
  const int l32 = lane & 31, hi = lane >> 5;

  const int id = blockIdx.x;
  const int bh = id & 31;
  const int c = 39 - (id >> 5);
  int qt, piece, np;
  if (c < 4)       { qt = c;                 piece = 0;            np = 1; }
  else if (c < 12) { int e = c - 4;  qt = 4 + (e >> 1); piece = e & 1; np = 2; }
  else if (c < 24) { int e = c - 12; qt = 8 + e / 3;    piece = e % 3; np = 3; }
  else             { int e = c - 24; qt = 12 + (e >> 2); piece = e & 3; np = 4; }
  const int total = qt + 1, bas = total / np, rem = total % np;
  const int len = bas + (piece < rem ? 1 : 0);
  const int k0 = piece * bas + (piece < rem ? piece : rem);

  const int b = bh >> 4, h = bh & 15;
  const int q_base = qt * 128;
  const size_t base = (size_t)b * SEQL * D_MODEL + h * DKH;

  // 32KB LDS, carved:
  //   Q phase : [0 .. 8192)            128 rows x 64 (swizzled)
  //   main    : Kh buf0 [0..4096) buf1 [4096..8192)   64 keys x 64 d
  //             Vh buf0 [8192..12288) buf1 [12288..16384)  64 d x 64 tok
  __shared__ bf16 lds[16384];

  const int r8 = lane >> 3, c8 = lane & 7;

  // ---- stage Q tile (128x64) swizzled, read qb frags ----
  for (int i = 0; i < 4; i++) {
    int row = wave * 32 + i * 8 + r8;
    int sc = c8 ^ (row & 7);
    gload_lds16(&Q[base + (size_t)(q_base + row) * D_MODEL + sc * 8],
                &lds[(wave * 32 + i * 8) * 64]);
  }
  __syncthreads();
  // B-operand frags of Q: col=l32=q row of this wave, k = ks*16 + hi*8 + j
  bf16x8 qb[4];
  {
    int row = wave * 32 + l32;
#pragma unroll
    for (int ks = 0; ks < 4; ks++) {
      int ch = (ks * 2 + hi) ^ (row & 7);
      qb[ks] = *(bf16x8*)&lds[row * 64 + ch * 8];
    }
  }
  __syncthreads();  // Q reads done before K staging overwrites

  f32x16 oaccT[2];  // [dt]: d = dt*32 + (r&3)+8*(r>>2)+4*hi, q = l32
  float lsum = 0.0f;
#pragma unroll
  for (int dt = 0; dt < 2; dt++)
#pragma unroll
    for (int r = 0; r < 16; r++) oaccT[dt][r] = 0.0f;

  const bf16* Vrow0 = &Vt_g[(size_t)(h * 64) * NROWS + b * SEQL];
  const int q_glob = q_base + wave * 32 + l32;

  // stage one 64-key half-tile (K: 64x64, V: 64 d x 64 tok), 4 loads/wave
  auto stage = [&](int hc) {
    int buf = hc & 1;
    int kb = k0 * 128 + hc * 64;
#pragma unroll
    for (int i = 0; i < 2; i++) {
      int seg = wave * 2 + i;     // 0..7
      int row = seg * 8 + r8;     // 0..63 (key row, and d row for V)
      int sc = c8 ^ (row & 7);
      gload_lds16(&K[base + (size_t)(kb + row) * D_MODEL + sc * 8],
                  &lds[buf * 4096 + seg * 512]);
      gload_lds16(&Vrow0[(size_t)row * NROWS + kb + sc * 8],
                  &lds[8192 + buf * 4096 + seg * 512]);
    }
  };

  const int nch = 2 * len;
  stage(0);
  for (int hc = 0; hc < nch; hc++) {
    if (hc + 1 < nch) {
      stage(hc + 1);
      asm volatile("s_waitcnt vmcnt(4)" ::: "memory");
    } else {
      asm volatile("s_waitcnt vmcnt(0)" ::: "memory");
    }
    __builtin_amdgcn_sched_barrier(0);
    __builtin_amdgcn_s_barrier();

    const int buf = hc & 1;
    const bf16* Kb_ = &lds[buf * 4096];
    const bf16* Vb_ = &lds[8192 + buf * 4096];
    const int kb = k0 * 128 + hc * 64;
    const bool diag = ((kb >> 7) == qt);

#pragma unroll
    for (int cc = 0; cc < 2; cc++) {  // 32-key chunks within the half-tile
      // ---- S^T chunk: 4 MFMA 32x32x16 over d ----
      f32x16 sT;
#pragma unroll
      for (int r = 0; r < 16; r++) sT[r] = 0.0f;
      {
        int krow = cc * 32 + l32;
#pragma unroll
        for (int ks = 0; ks < 4; ks++) {
          int ch = (ks * 2 + hi) ^ (krow & 7);
          bf16x8 kf = *(bf16x8*)&Kb_[krow * 64 + ch * 8];
          sT = mfma32(kf, qb[ks], sT);
        }
      }
      if (diag) {
#pragma unroll
        for (int r = 0; r < 16; r++) {
          int key = kb + cc * 32 + (r & 3) + 8 * (r >> 2) + 4 * hi;
          if (key > q_glob) sT[r] = -1e30f;
        }
      }
      // ---- raw v_exp_f32 ----
      float p[16];
#pragma unroll
      for (int r = 0; r < 16; r++) p[r] = fexp2(sT[r]);
      // ---- l partial (VALU tree; cross-hi combine in epilogue) ----
      lsum += (((p[0] + p[1]) + (p[2] + p[3])) +
               ((p[4] + p[5]) + (p[6] + p[7]))) +
              (((p[8] + p[9]) + (p[10] + p[11])) +
               ((p[12] + p[13]) + (p[14] + p[15])));
      // ---- in-register P -> B-operand frags (T12) ----
      unsigned a0 = cvt_pk(p[0], p[1]),  a1 = cvt_pk(p[2], p[3]);
      unsigned b0 = cvt_pk(p[4], p[5]),  b1 = cvt_pk(p[6], p[7]);
      unsigned c0 = cvt_pk(p[8], p[9]),  c1 = cvt_pk(p[10], p[11]);
      unsigned d0 = cvt_pk(p[12], p[13]), d1 = cvt_pk(p[14], p[15]);
      plswap(a0, b0); plswap(a1, b1); plswap(c0, d0); plswap(c1, d1);
      bf16x8 pf[2];
      {
        u32x4 u = {a0, a1, b0, b1};  // keys hi*8+0..7 (k-step 0)
        pf[0] = __builtin_bit_cast(bf16x8, u);
      }
      {
        u32x4 u = {c0, c1, d0, d1};  // keys 16 + hi*8+0..7 (k-step 1)
        pf[1] = __builtin_bit_cast(bf16x8, u);
      }
      // ---- PV: 4 MFMA 32x32x16 ----
#pragma unroll
      for (int dt = 0; dt < 2; dt++) {
        int d = dt * 32 + l32;
#pragma unroll
        for (int ks = 0; ks < 2; ks++) {
          int ch = (cc * 4 + ks * 2 + hi) ^ (d & 7);
          bf16x8 vf = *(bf16x8*)&Vb_[d * 64 + ch * 8];
          oaccT[dt] = mfma32(vf, pf[ks], oaccT[dt]);
        }
      }
    }
    asm volatile("" ::: "memory");
    __builtin_amdgcn_sched_barrier(0);
    __builtin_amdgcn_s_barrier();
  }

  // ---- write partials: piece p -> slice p, plain coalesced stores ----
  lsum += __shfl_xor(lsum, 32);  // combine hi halves: full row-sum per q
  float* Ob;
  float* Lb;
  int rbase, roff;
  if (piece == 0)      { Ob = O0; Lb = L0; rbase = SEQL;        roff = 0; }
  else if (piece == 1) { Ob = O1; Lb = L1; rbase = SEQL - 512;  roff = 512; }
  else if (piece == 2) { Ob = O2; Lb = L2; rbase = SEQL - 1024; roff = 1024; }
  else                 { Ob = O3; Lb = L3; rbase = SEQL - 1536; roff = 1536; }
  {
    int qrow = q_base + wave * 32 + l32;
    size_t orow = (size_t)b * rbase + (qrow - roff);
    if (hi == 0) Lb[orow * NHEADS + h] = lsum;
#pragma unroll
    for (int dt = 0; dt < 2; dt++)
#pragma unroll
      for (int rq = 0; rq < 4; rq++) {
        f32x4 vv = {oaccT[dt][rq * 4 + 0], oaccT[dt][rq * 4 + 1],
                    oaccT[dt][rq * 4 + 2], oaccT[dt][rq * 4 + 3]};
        *(f32x4*)&Ob[orow * D_MODEL + h * DKH + dt * 32 + rq * 8 + hi * 4] =
            vv;
      }
  }
}

// ---------------------------------------------------------------------------
extern "C" void kernel_launch(void* const* d_in, const int* in_sizes, int n_in,
                              void* d_out, int out_size, void* d_ws,
                              size_t ws_size, hipStream_t stream) {
  const float* x = (const float*)d_in[0];
  const float* wq = (const float*)d_in[1];
  const float* wk = (const float*)d_in[2];
  const float* wv = (const float*)d_in[3];
  const float* wo = (const float*)d_in[4];
  const int* tpos = (const int*)d_in[6];
  float* out = (float*)d_out;

  char* p = (char*)d_ws;
  bf16* xb  = (bf16*)p; p += (size_t)NROWS * D_MODEL * 2;    // 8.39 MB
  bf16* wqb = (bf16*)p; p += (size_t)D_MODEL * D_MODEL * 2;  // 2.10 MB
  bf16* wkb = (bf16*)p; p += (size_t)D_MODEL * D_MODEL * 2;
  bf16* wvb = (bf16*)p; p += (size_t)D_MODEL * D_MODEL * 2;
  bf16* wob = (bf16*)p; p += (size_t)D_MODEL * D_MODEL * 2;
  bf16* Qb  = (bf16*)p; p += (size_t)NROWS * D_MODEL * 2;
  bf16* Kb  = (bf16*)p; p += (size_t)NROWS * D_MODEL * 2;
  bf16* Vt  = (bf16*)p; p += (size_t)NROWS * D_MODEL * 2;    // [e][token]
  bf16* Cc  = (bf16*)p; p += (size_t)NROWS * D_MODEL * 2;    // (unused, R16)
  float* O0 = (float*)p; p += (size_t)NROWS * D_MODEL * 4;
  float* L0 = (float*)p; p += (size_t)NROWS * NHEADS * 4;
  float* O1 = (float*)p; p += (size_t)NBATCH * (SEQL - 512) * D_MODEL * 4;
  float* L1 = (float*)p; p += (size_t)NBATCH * (SEQL - 512) * NHEADS * 4;
  float* O2 = (float*)xb;
  float* O3 = (float*)wqb;
  float* L2 = (float*)wvb;
  float* L3 = (float*)wvb + (size_t)NBATCH * (SEQL - 1024) * NHEADS;
  (void)Cc;

  convert_kernel<<<8192, 256, 0, stream>>>(x, wq, wk, wv, wo, xb, wqb, wkb,
                                           wvb, wob);
  qkv_gemm<<<dim3(NROWS / 128, D_MODEL / 64), 256, 0, stream>>>(
      xb, wqb, wkb, wvb, tpos, Qb, Kb, Vt);
  attn_kernel<<<1280, 256, 0, stream>>>(Qb, Kb, Vt, O0, O1, O2, O3, L0, L1,
                                        L2, L3);
  og_norm<<<dim3(NROWS / 64, D_MODEL / 128), 256, 0, stream>>>(
      O0, O1, O2, O3, L0, L1, L2, L3, wob, out);
}

// Round 8
// 179.470 us; speedup vs baseline: 1.4530x; 1.4530x over previous
//
#include <hip/hip_runtime.h>
#include <cstdint>

#define D_MODEL 1024
#define NHEADS 16
#define DKH 64
#define SEQL 2048
#define NBATCH 2
#define NROWS (NBATCH * SEQL) /* 4096 */

typedef __bf16 bf16;
typedef __bf16 bf16x2 __attribute__((ext_vector_type(2)));
typedef __bf16 bf16x4 __attribute__((ext_vector_type(4)));
typedef __bf16 bf16x8 __attribute__((ext_vector_type(8)));
typedef float f32x4 __attribute__((ext_vector_type(4)));
typedef float f32x16 __attribute__((ext_vector_type(16)));
typedef unsigned u32x4 __attribute__((ext_vector_type(4)));

static __device__ __forceinline__ f32x4 mfma16(bf16x8 a, bf16x8 b, f32x4 c) {
  return __builtin_amdgcn_mfma_f32_16x16x32_bf16(a, b, c, 0, 0, 0);
}

static __device__ __forceinline__ f32x16 mfma32(bf16x8 a, bf16x8 b, f32x16 c) {
  return __builtin_amdgcn_mfma_f32_32x32x16_bf16(a, b, c, 0, 0, 0);
}

static __device__ __forceinline__ void gload_lds16(const bf16* g, bf16* l) {
  __builtin_amdgcn_global_load_lds(
      (const __attribute__((address_space(1))) void*)g,
      (__attribute__((address_space(3))) void*)l, 16, 0, 0);
}

// raw v_exp_f32 (libm exp2f adds ~10 range-check instrs; HW handles our full
// input range incl. -1e30 -> 0)
static __device__ __forceinline__ float fexp2(float x) {
  return __builtin_amdgcn_exp2f(x);
}

// pack two f32 -> one dword of two bf16 (RNE), lo = a, hi = b
static __device__ __forceinline__ unsigned cvt_pk(float a, float b) {
  unsigned r;
  asm("v_cvt_pk_bf16_f32 %0, %1, %2" : "=v"(r) : "v"(a), "v"(b));
  return r;
}

// swap lanes 32-63 of a with lanes 0-31 of b (VALU pipe, not LDS)
static __device__ __forceinline__ void plswap(unsigned& a, unsigned& b) {
  asm("v_permlane32_swap_b32 %0, %1" : "+v"(a), "+v"(b));
}

// ---------------------------------------------------------------------------
// fp32 -> bf16 conversion of x and the 4 weight matrices.
// ---------------------------------------------------------------------------
__global__ __launch_bounds__(256) void convert_kernel(
    const float* __restrict__ x, const float* __restrict__ wq,
    const float* __restrict__ wk, const float* __restrict__ wv,
    const float* __restrict__ wo, bf16* __restrict__ xb,
    bf16* __restrict__ wqb, bf16* __restrict__ wkb, bf16* __restrict__ wvb,
    bf16* __restrict__ wob) {
  int i4 = blockIdx.x * 256 + threadIdx.x;
  const float* src;
  bf16* dst;
  int off;
  if (i4 < (NROWS * D_MODEL / 4)) {
    src = x; dst = xb; off = i4;
  } else {
    int j = i4 - NROWS * D_MODEL / 4;
    int sel = j >> 18;
    off = j & ((1 << 18) - 1);
    src = sel == 0 ? wq : sel == 1 ? wk : sel == 2 ? wv : wo;
    dst = sel == 0 ? wqb : sel == 1 ? wkb : sel == 2 ? wvb : wob;
  }
  float4 v = ((const float4*)src)[off];
  bf16x4 o;
  o[0] = (bf16)v.x; o[1] = (bf16)v.y; o[2] = (bf16)v.z; o[3] = (bf16)v.w;
  ((bf16x4*)dst)[off] = o;
}

// ---------------------------------------------------------------------------
// FUSED QKV GEMM + RoPE. One block: Q,K,V for (128 tokens x 64 e-cols);
// A tile staged once, 3 B tiles together (MFMA:glds = 48:10). RoPE applied
// to the f32 Q/K accumulators in the epilogue: the (even,odd) column pair
// lives in adjacent lanes (l16^1) -> __shfl_xor(v,1); Q pre-scaled by
// 0.125*log2e. V stored transposed (Vt[e][token]) via packed b64 stores.
// LDS: A 16K + 3x8K = 40960 B.
// ---------------------------------------------------------------------------
__global__ __launch_bounds__(256, 3) void qkv_gemm(
    const bf16* __restrict__ A, const bf16* __restrict__ Bq,
    const bf16* __restrict__ Bk, const bf16* __restrict__ Bv,
    const int* __restrict__ tpos, bf16* __restrict__ Qb,
    bf16* __restrict__ Kb, bf16* __restrict__ Vt) {
  __shared__ bf16 As[128 * 64];
  __shared__ bf16 Bs[3][64 * 64];
  const int t = threadIdx.x, wave = t >> 6, lane = t & 63;
  const int quad = lane >> 4, l16 = lane & 15;
  const int bm = blockIdx.x * 128, bn = blockIdx.y * 64;

  f32x4 acc[3][2][4];
  for (int o = 0; o < 3; o++)
    for (int mt = 0; mt < 2; mt++)
      for (int nt = 0; nt < 4; nt++)
        for (int r = 0; r < 4; r++) acc[o][mt][nt][r] = 0.0f;

  for (int k0 = 0; k0 < D_MODEL; k0 += 64) {
    for (int j = 0; j < 4; j++) {
      int s = (wave * 4 + j) * 64 + lane;
      int srow = s >> 3, scol = (s & 7) ^ (srow & 7);
      gload_lds16(&A[(size_t)(bm + srow) * D_MODEL + k0 + scol * 8],
                  &As[(wave * 4 + j) * 512]);
    }
    for (int j = 0; j < 2; j++) {
      int s = (wave * 2 + j) * 64 + lane;
      int srow = s >> 3, scol = (s & 7) ^ (srow & 7);
      size_t goff = (size_t)(bn + srow) * D_MODEL + k0 + scol * 8;
      gload_lds16(&Bq[goff], &Bs[0][(wave * 2 + j) * 512]);
      gload_lds16(&Bk[goff], &Bs[1][(wave * 2 + j) * 512]);
      gload_lds16(&Bv[goff], &Bs[2][(wave * 2 + j) * 512]);
    }
    __syncthreads();
    for (int kh = 0; kh < 2; kh++) {
      const int kc = kh * 4 + quad;
      bf16x8 af[2];
      for (int mt = 0; mt < 2; mt++) {
        int row = wave * 32 + mt * 16 + l16;
        af[mt] = *(bf16x8*)&As[row * 64 + (kc ^ (row & 7)) * 8];
      }
      for (int nt = 0; nt < 4; nt++) {
        int row = nt * 16 + l16;
        int off = row * 64 + (kc ^ (row & 7)) * 8;
        bf16x8 bq = *(bf16x8*)&Bs[0][off];
        bf16x8 bk = *(bf16x8*)&Bs[1][off];
        bf16x8 bv = *(bf16x8*)&Bs[2][off];
        for (int mt = 0; mt < 2; mt++) {
          acc[0][mt][nt] = mfma16(af[mt], bq, acc[0][mt][nt]);
          acc[1][mt][nt] = mfma16(af[mt], bk, acc[1][mt][nt]);
          acc[2][mt][nt] = mfma16(af[mt], bv, acc[2][mt][nt]);
        }
      }
    }
    __syncthreads();
  }

  // ---- epilogue: RoPE on Q,K (f32 regs, pair via shfl), stores ----
  const float qsc = 0.125f * 1.44269504f;
  float freqv[4], sgn[4];
  for (int nt = 0; nt < 4; nt++) {
    int cp = (bn + nt * 16 + l16) & 63;
    freqv[nt] = fexp2((float)(cp >> 1) * -0.41524101f);  // 10000^(-p/32)
    sgn[nt] = (cp & 1) ? 1.0f : -1.0f;
  }
  for (int mt = 0; mt < 2; mt++) {
    int row0 = bm + wave * 32 + mt * 16 + quad * 4;
    for (int r = 0; r < 4; r++) {
      int row = row0 + r;
      float pos = (float)tpos[row & (SEQL - 1)];
      for (int nt = 0; nt < 4; nt++) {
        int col = bn + nt * 16 + l16;
        float sn, cs;
        __sincosf(pos * freqv[nt], &sn, &cs);
        float vq = acc[0][mt][nt][r];
        float vk = acc[1][mt][nt][r];
        float pq = __shfl_xor(vq, 1);
        float pk = __shfl_xor(vk, 1);
        float rq = vq * cs + sgn[nt] * pq * sn;
        float rk = vk * cs + sgn[nt] * pk * sn;
        Qb[(size_t)row * D_MODEL + col] = (bf16)(rq * qsc);
        Kb[(size_t)row * D_MODEL + col] = (bf16)rk;
      }
    }
    for (int nt = 0; nt < 4; nt++) {
      int col = bn + nt * 16 + l16;
      bf16x4 pv;
      for (int r = 0; r < 4; r++) pv[r] = (bf16)acc[2][mt][nt][r];
      *(bf16x4*)&Vt[(size_t)col * NROWS + row0] = pv;  // transposed, packed
    }
  }
}

// ---------------------------------------------------------------------------
// o_gemm, R15 (kept from R6): 2-phase double-buffered counted-vmcnt.
// stage(t+1) issued BEFORE the wait; steady state s_waitcnt vmcnt(6),
// vmcnt(0) only at the last step. LDS 48KB keeps 3 blocks/CU.
// ---------------------------------------------------------------------------
__global__ __launch_bounds__(256, 3) void o_gemm(const bf16* __restrict__ A,
                                                 const bf16* __restrict__ Bm,
                                                 float* __restrict__ C) {
  constexpr int BM = 64, BN = 128, MT = 2, NT = 4, CA = 2, CB = 4;
  const int K = D_MODEL, N = D_MODEL;
  const int bm = blockIdx.x * BM, bn = blockIdx.y * BN;
  __shared__ bf16 As[2][BM * 64];
  __shared__ bf16 Bs[2][BN * 64];
  const int t = threadIdx.x;
  const int wave = t >> 6, lane = t & 63;
  const int quad = lane >> 4, l16 = lane & 15;
  const int wm = (wave >> 1) * (MT * 16), wn = (wave & 1) * (NT * 16);

  f32x4 acc[MT][NT];
  for (int i = 0; i < MT; i++)
    for (int j = 0; j < NT; j++)
      for (int r = 0; r < 4; r++) acc[i][j][r] = 0.0f;

  auto stage = [&](int buf, int k0) {
#pragma unroll
    for (int j = 0; j < CA; j++) {
      int s = (wave * CA + j) * 64 + lane;
      int srow = s >> 3, scol = (s & 7) ^ (srow & 7);
      gload_lds16(&A[(size_t)(bm + srow) * K + k0 + scol * 8],
                  &As[buf][(wave * CA + j) * 512]);
    }
#pragma unroll
    for (int j = 0; j < CB; j++) {
      int s = (wave * CB + j) * 64 + lane;
      int srow = s >> 3, scol = (s & 7) ^ (srow & 7);
      gload_lds16(&Bm[(size_t)(bn + srow) * K + k0 + scol * 8],
                  &Bs[buf][(wave * CB + j) * 512]);
    }
  };

  stage(0, 0);
  int cur = 0;
  for (int kt = 0; kt < K / 64; kt++) {
    if (kt + 1 < K / 64) {
      stage(cur ^ 1, (kt + 1) * 64);
      asm volatile("s_waitcnt vmcnt(6)" ::: "memory");
    } else {
      asm volatile("s_waitcnt vmcnt(0)" ::: "memory");
    }
    __builtin_amdgcn_sched_barrier(0);
    __builtin_amdgcn_s_barrier();

#pragma unroll
    for (int kh = 0; kh < 2; kh++) {
      const int kc = kh * 4 + quad;
      bf16x8 af[MT], bfr[NT];
#pragma unroll
      for (int mt = 0; mt < MT; mt++) {
        int row = wm + mt * 16 + l16;
        af[mt] = *(bf16x8*)&As[cur][row * 64 + (kc ^ (row & 7)) * 8];
      }
#pragma unroll
      for (int nt = 0; nt < NT; nt++) {
        int row = wn + nt * 16 + l16;
        bfr[nt] = *(bf16x8*)&Bs[cur][row * 64 + (kc ^ (row & 7)) * 8];
      }
#pragma unroll
      for (int mt = 0; mt < MT; mt++)
#pragma unroll
        for (int nt = 0; nt < NT; nt++)
          acc[mt][nt] = mfma16(af[mt], bfr[nt], acc[mt][nt]);
    }
    asm volatile("" ::: "memory");
    __builtin_amdgcn_sched_barrier(0);
    __builtin_amdgcn_s_barrier();
    cur ^= 1;
  }
  for (int mt = 0; mt < MT; mt++)
    for (int nt = 0; nt < NT; nt++)
      for (int r = 0; r < 4; r++) {
        int row = bm + wm + mt * 16 + quad * 4 + r;
        int col = bn + wn + nt * 16 + l16;
        C[(size_t)row * N + col] = acc[mt][nt][r];
      }
}

// ---------------------------------------------------------------------------
// Flash attention, causal, transposed-score, static-scale, no atomics.
// R12/R3 structure (best measured: attn <= 40.8us) + R17: T5 setprio(1)
// around the QK^T and PV MFMA clusters. Mechanism: waves progress through
// the cc-chunk loop independently between half-tile barriers (role split:
// some waves in softmax-VALU, some in MFMA) -> scheduler can prefer the
// MFMA-entering wave (m191: +4-7% on attn). Everything else identical.
// ---------------------------------------------------------------------------
__global__ __launch_bounds__(256) void attn_kernel(
    const bf16* __restrict__ Q, const bf16* __restrict__ K,
    const bf16* __restrict__ Vt_g, float* __restrict__ O0,
    float* __restrict__ O1, float* __restrict__ O2, float* __restrict__ O3,
    float* __restrict__ L0, float* __restrict__ L1, float* __restrict__ L2,
    float* __restrict__ L3) {
  const int t = threadIdx.x;
  const int wave = t >> 6, lane = t & 63;
  const int l32 = lane & 31, hi = lane >> 5;

  const int id = blockIdx.x;
  const int bh = id & 31;
  const int c = 39 - (id >> 5);
  int qt, piece, np;
  if (c < 4)       { qt = c;                 piece = 0;            np = 1; }
  else if (c < 12) { int e = c - 4;  qt = 4 + (e >> 1); piece = e & 1; np = 2; }
  else if (c < 24) { int e = c - 12; qt = 8 + e / 3;    piece = e % 3; np = 3; }
  else             { int e = c - 24; qt = 12 + (e >> 2); piece = e & 3; np = 4; }
  const int total = qt + 1, bas = total / np, rem = total % np;
  const int len = bas + (piece < rem ? 1 : 0);
  const int k0 = piece * bas + (piece < rem ? piece : rem);

  const int b = bh >> 4, h = bh & 15;
  const int q_base = qt * 128;
  const size_t base = (size_t)b * SEQL * D_MODEL + h * DKH;

  // 32KB LDS, carved:
  //   Q phase : [0 .. 8192)            128 rows x 64 (swizzled)
  //   main    : Kh buf0 [0..4096) buf1 [4096..8192)   64 keys x 64 d
  //             Vh buf0 [8192..12288) buf1 [12288..16384)  64 d x 64 tok
  __shared__ bf16 lds[16384];

  const int r8 = lane >> 3, c8 = lane & 7;

  // ---- stage Q tile (128x64) swizzled, read qb frags ----
  for (int i = 0; i < 4; i++) {
    int row = wave * 32 + i * 8 + r8;
    int sc = c8 ^ (row & 7);
    gload_lds16(&Q[base + (size_t)(q_base + row) * D_MODEL + sc * 8],
                &lds[(wave * 32 + i * 8) * 64]);
  }
  __syncthreads();
  // B-operand frags of Q: col=l32=q row of this wave, k = ks*16 + hi*8 + j
  bf16x8 qb[4];
  {
    int row = wave * 32 + l32;
#pragma unroll
    for (int ks = 0; ks < 4; ks++) {
      int ch = (ks * 2 + hi) ^ (row & 7);
      qb[ks] = *(bf16x8*)&lds[row * 64 + ch * 8];
    }
  }
  __syncthreads();  // Q reads done before K staging overwrites

  f32x16 oaccT[2];  // [dt]: d = dt*32 + (r&3)+8*(r>>2)+4*hi, q = l32
  float lsum = 0.0f;
#pragma unroll
  for (int dt = 0; dt < 2; dt++)
#pragma unroll
    for (int r = 0; r < 16; r++) oaccT[dt][r] = 0.0f;

  const bf16* Vrow0 = &Vt_g[(size_t)(h * 64) * NROWS + b * SEQL];
  const int q_glob = q_base + wave * 32 + l32;

  // stage one 64-key half-tile (K: 64x64, V: 64 d x 64 tok), 4 loads/wave
  auto stage = [&](int hc) {
    int buf = hc & 1;
    int kb = k0 * 128 + hc * 64;
#pragma unroll
    for (int i = 0; i < 2; i++) {
      int seg = wave * 2 + i;     // 0..7
      int row = seg * 8 + r8;     // 0..63 (key row, and d row for V)
      int sc = c8 ^ (row & 7);
      gload_lds16(&K[base + (size_t)(kb + row) * D_MODEL + sc * 8],
                  &lds[buf * 4096 + seg * 512]);
      gload_lds16(&Vrow0[(size_t)row * NROWS + kb + sc * 8],
                  &lds[8192 + buf * 4096 + seg * 512]);
    }
  };

  const int nch = 2 * len;
  stage(0);
  for (int hc = 0; hc < nch; hc++) {
    if (hc + 1 < nch) {
      stage(hc + 1);
      asm volatile("s_waitcnt vmcnt(4)" ::: "memory");
    } else {
      asm volatile("s_waitcnt vmcnt(0)" ::: "memory");
    }
    __builtin_amdgcn_sched_barrier(0);
    __builtin_amdgcn_s_barrier();

    const int buf = hc & 1;
    const bf16* Kb_ = &lds[buf * 4096];
    const bf16* Vb_ = &lds[8192 + buf * 4096];
    const int kb = k0 * 128 + hc * 64;
    const bool diag = ((kb >> 7) == qt);

#pragma unroll
    for (int cc = 0; cc < 2; cc++) {  // 32-key chunks within the half-tile
      // ---- S^T chunk: 4 MFMA 32x32x16 over d ----
      f32x16 sT;
#pragma unroll
      for (int r = 0; r < 16; r++) sT[r] = 0.0f;
      {
        int krow = cc * 32 + l32;
        __builtin_amdgcn_s_setprio(1);
#pragma unroll
        for (int ks = 0; ks < 4; ks++) {
          int ch = (ks * 2 + hi) ^ (krow & 7);
          bf16x8 kf = *(bf16x8*)&Kb_[krow * 64 + ch * 8];
          sT = mfma32(kf, qb[ks], sT);
        }
        __builtin_amdgcn_s_setprio(0);
      }
      if (diag) {
#pragma unroll
        for (int r = 0; r < 16; r++) {
          int key = kb + cc * 32 + (r & 3) + 8 * (r >> 2) + 4 * hi;
          if (key > q_glob) sT[r] = -1e30f;
        }
      }
      // ---- raw v_exp_f32 ----
      float p[16];
#pragma unroll
      for (int r = 0; r < 16; r++) p[r] = fexp2(sT[r]);
      // ---- l partial (VALU tree; cross-hi combine in epilogue) ----
      lsum += (((p[0] + p[1]) + (p[2] + p[3])) +
               ((p[4] + p[5]) + (p[6] + p[7]))) +
              (((p[8] + p[9]) + (p[10] + p[11])) +
               ((p[12] + p[13]) + (p[14] + p[15])));
      // ---- in-register P -> B-operand frags (T12) ----
      unsigned a0 = cvt_pk(p[0], p[1]),  a1 = cvt_pk(p[2], p[3]);
      unsigned b0 = cvt_pk(p[4], p[5]),  b1 = cvt_pk(p[6], p[7]);
      unsigned c0 = cvt_pk(p[8], p[9]),  c1 = cvt_pk(p[10], p[11]);
      unsigned d0 = cvt_pk(p[12], p[13]), d1 = cvt_pk(p[14], p[15]);
      plswap(a0, b0); plswap(a1, b1); plswap(c0, d0); plswap(c1, d1);
      bf16x8 pf[2];
      {
        u32x4 u = {a0, a1, b0, b1};  // keys hi*8+0..7 (k-step 0)
        pf[0] = __builtin_bit_cast(bf16x8, u);
      }
      {
        u32x4 u = {c0, c1, d0, d1};  // keys 16 + hi*8+0..7 (k-step 1)
        pf[1] = __builtin_bit_cast(bf16x8, u);
      }
      // ---- PV: 4 MFMA 32x32x16 ----
      __builtin_amdgcn_s_setprio(1);
#pragma unroll
      for (int dt = 0; dt < 2; dt++) {
        int d = dt * 32 + l32;
#pragma unroll
        for (int ks = 0; ks < 2; ks++) {
          int ch = (cc * 4 + ks * 2 + hi) ^ (d & 7);
          bf16x8 vf = *(bf16x8*)&Vb_[d * 64 + ch * 8];
          oaccT[dt] = mfma32(vf, pf[ks], oaccT[dt]);
        }
      }
      __builtin_amdgcn_s_setprio(0);
    }
    asm volatile("" ::: "memory");
    __builtin_amdgcn_sched_barrier(0);
    __builtin_amdgcn_s_barrier();
  }

  // ---- write partials: piece p -> slice p, plain coalesced stores ----
  lsum += __shfl_xor(lsum, 32);  // combine hi halves: full row-sum per q
  float* Ob;
  float* Lb;
  int rbase, roff;
  if (piece == 0)      { Ob = O0; Lb = L0; rbase = SEQL;        roff = 0; }
  else if (piece == 1) { Ob = O1; Lb = L1; rbase = SEQL - 512;  roff = 512; }
  else if (piece == 2) { Ob = O2; Lb = L2; rbase = SEQL - 1024; roff = 1024; }
  else                 { Ob = O3; Lb = L3; rbase = SEQL - 1536; roff = 1536; }
  {
    int qrow = q_base + wave * 32 + l32;
    size_t orow = (size_t)b * rbase + (qrow - roff);
    if (hi == 0) Lb[orow * NHEADS + h] = lsum;
#pragma unroll
    for (int dt = 0; dt < 2; dt++)
#pragma unroll
      for (int rq = 0; rq < 4; rq++) {
        f32x4 vv = {oaccT[dt][rq * 4 + 0], oaccT[dt][rq * 4 + 1],
                    oaccT[dt][rq * 4 + 2], oaccT[dt][rq * 4 + 3]};
        *(f32x4*)&Ob[orow * D_MODEL + h * DKH + dt * 32 + rq * 8 + hi * 4] =
            vv;
      }
  }
}

// ---------------------------------------------------------------------------
// normalize: sum applicable slices, divide by summed l, write bf16 Cc.
// ---------------------------------------------------------------------------
__global__ __launch_bounds__(256) void normalize_kernel(
    const float* __restrict__ O0, const float* __restrict__ O1,
    const float* __restrict__ O2, const float* __restrict__ O3,
    const float* __restrict__ L0, const float* __restrict__ L1,
    const float* __restrict__ L2, const float* __restrict__ L3,
    bf16* __restrict__ Cc) {
  int i4 = blockIdx.x * 256 + threadIdx.x;
  int row = i4 >> 8;
  int c0 = (i4 & 255) * 4;
  int s = row & (SEQL - 1);
  int b = row >> 11;
  int h = c0 >> 6;
  float l = L0[(size_t)row * NHEADS + h];
  f32x4 v = *(const f32x4*)&O0[(size_t)row * D_MODEL + c0];
  if (s >= 512) {
    size_t r1 = (size_t)b * (SEQL - 512) + (s - 512);
    l += L1[r1 * NHEADS + h];
    f32x4 u = *(const f32x4*)&O1[r1 * D_MODEL + c0];
    for (int r = 0; r < 4; r++) v[r] += u[r];
  }
  if (s >= 1024) {
    size_t r2 = (size_t)b * (SEQL - 1024) + (s - 1024);
    l += L2[r2 * NHEADS + h];
    f32x4 u = *(const f32x4*)&O2[r2 * D_MODEL + c0];
    for (int r = 0; r < 4; r++) v[r] += u[r];
  }
  if (s >= 1536) {
    size_t r3 = (size_t)b * (SEQL - 1536) + (s - 1536);
    l += L3[r3 * NHEADS + h];
    f32x4 u = *(const f32x4*)&O3[r3 * D_MODEL + c0];
    for (int r = 0; r < 4; r++) v[r] += u[r];
  }
  float inv = 1.0f / l;
  bf16x4 o;
  o[0] = (bf16)(v[0] * inv);
  o[1] = (bf16)(v[1] * inv);
  o[2] = (bf16)(v[2] * inv);
  o[3] = (bf16)(v[3] * inv);
  *(bf16x4*)&Cc[(size_t)row * D_MODEL + c0] = o;
}

// ---------------------------------------------------------------------------
extern "C" void kernel_launch(void* const* d_in, const int* in_sizes, int n_in,
                              void* d_out, int out_size, void* d_ws,
                              size_t ws_size, hipStream_t stream) {
  const float* x = (const float*)d_in[0];
  const float* wq = (const float*)d_in[1];
  const float* wk = (const float*)d_in[2];
  const float* wv = (const float*)d_in[3];
  const float* wo = (const float*)d_in[4];
  const int* tpos = (const int*)d_in[6];
  float* out = (float*)d_out;

  char* p = (char*)d_ws;
  bf16* xb  = (bf16*)p; p += (size_t)NROWS * D_MODEL * 2;    // 8.39 MB
  bf16* wqb = (bf16*)p; p += (size_t)D_MODEL * D_MODEL * 2;  // 2.10 MB
  bf16* wkb = (bf16*)p; p += (size_t)D_MODEL * D_MODEL * 2;
  bf16* wvb = (bf16*)p; p += (size_t)D_MODEL * D_MODEL * 2;
  bf16* wob = (bf16*)p; p += (size_t)D_MODEL * D_MODEL * 2;
  bf16* Qb  = (bf16*)p; p += (size_t)NROWS * D_MODEL * 2;
  bf16* Kb  = (bf16*)p; p += (size_t)NROWS * D_MODEL * 2;
  bf16* Vt  = (bf16*)p; p += (size_t)NROWS * D_MODEL * 2;    // [e][token]
  bf16* Cc  = (bf16*)p; p += (size_t)NROWS * D_MODEL * 2;
  float* O0 = (float*)p; p += (size_t)NROWS * D_MODEL * 4;
  float* L0 = (float*)p; p += (size_t)NROWS * NHEADS * 4;
  float* O1 = (float*)p; p += (size_t)NBATCH * (SEQL - 512) * D_MODEL * 4;
  float* L1 = (float*)p; p += (size_t)NBATCH * (SEQL - 512) * NHEADS * 4;
  float* O2 = (float*)xb;
  float* O3 = (float*)wqb;
  float* L2 = (float*)wvb;
  float* L3 = (float*)wvb + (size_t)NBATCH * (SEQL - 1024) * NHEADS;

  convert_kernel<<<8192, 256, 0, stream>>>(x, wq, wk, wv, wo, xb, wqb, wkb,
                                           wvb, wob);
  qkv_gemm<<<dim3(NROWS / 128, D_MODEL / 64), 256, 0, stream>>>(
      xb, wqb, wkb, wvb, tpos, Qb, Kb, Vt);
  attn_kernel<<<1280, 256, 0, stream>>>(Qb, Kb, Vt, O0, O1, O2, O3, L0, L1,
                                        L2, L3);
  normalize_kernel<<<NROWS * D_MODEL / 1024, 256, 0, stream>>>(
      O0, O1, O2, O3, L0, L1, L2, L3, Cc);
  o_gemm<<<dim3(NROWS / 64, D_MODEL / 128), 256, 0, stream>>>(Cc, wob, out);
}